// Round 1
// baseline (1695.905 us; speedup 1.0000x reference)
//
#include <hip/hip_runtime.h>
#include <hip/hip_bf16.h>

#define TOKENS 8192
#define HID 4096
#define NEXP 8
#define INTER 2048
#define VOCABM1 31999
#define MAXROWS 9216          // 8192 + 8*128 padding
#define MAXTILES 72

typedef float f32x4 __attribute__((ext_vector_type(4)));
typedef __bf16 bf16x8 __attribute__((ext_vector_type(8)));
typedef short sh4 __attribute__((ext_vector_type(4)));

// ---- workspace layout (byte offsets) ----
#define WS_NTILES  0
#define WS_TEXP    64
#define WS_TROW    512
#define WS_TNV     1024
#define WS_PERM    4096
#define WS_ROWTOK  40960
#define WS_XS      131072
#define WS_INTER   (WS_XS + (size_t)MAXROWS * HID * 2)
#define WS_NEED    (WS_INTER + (size_t)MAXROWS * INTER * 2)

__device__ __forceinline__ int iclamp(int v, int lo, int hi) {
    return v < lo ? lo : (v > hi ? hi : v);
}
__device__ __forceinline__ unsigned short f2b(float f) {
    __hip_bfloat16 h = __float2bfloat16(f);
    unsigned short u; __builtin_memcpy(&u, &h, 2); return u;
}
__device__ __forceinline__ unsigned pk2(float a, float b) {
    return (unsigned)f2b(a) | ((unsigned)f2b(b) << 16);
}
__device__ __forceinline__ void gld16(const void* g, void* l) {
    __builtin_amdgcn_global_load_lds((const __attribute__((address_space(1))) void*)g,
                                     (__attribute__((address_space(3))) void*)l,
                                     16, 0, 0);
}
__device__ __forceinline__ bf16x8 ldfrag(const unsigned short* p) {
    sh4 lo = *(const sh4*)p;
    sh4 hi = *(const sh4*)(p + 4);
    struct { sh4 a, b; } s{lo, hi};
    return __builtin_bit_cast(bf16x8, s);
}

// ---------------- routing ----------------
__global__ void route_kernel(const int* __restrict__ ids, char* __restrict__ ws) {
    __shared__ int cnt[NEXP], base[NEXP], cur[NEXP];
    int tid = threadIdx.x;
    if (tid < NEXP) { cnt[tid] = 0; cur[tid] = 0; }
    __syncthreads();
    for (int i = tid; i < TOKENS; i += blockDim.x) {
        int v = iclamp(ids[i], 0, VOCABM1);
        atomicAdd(&cnt[v & 7], 1);
    }
    __syncthreads();
    if (tid == 0) {
        int* texp = (int*)(ws + WS_TEXP);
        int* trow = (int*)(ws + WS_TROW);
        int* tnv  = (int*)(ws + WS_TNV);
        int pb = 0, ntl = 0;
        for (int e = 0; e < NEXP; e++) {
            base[e] = pb;
            int ne = cnt[e];
            int t = (ne + 127) >> 7;
            for (int j = 0; j < t; j++) {
                texp[ntl] = e;
                trow[ntl] = pb + j * 128;
                int rem = ne - j * 128;
                tnv[ntl] = rem < 128 ? rem : 128;
                ntl++;
            }
            pb += t * 128;
        }
        *(int*)(ws + WS_NTILES) = ntl;
    }
    __syncthreads();
    int* perm = (int*)(ws + WS_PERM);
    int* rt   = (int*)(ws + WS_ROWTOK);
    for (int i = tid; i < TOKENS; i += blockDim.x) {
        int v = iclamp(ids[i], 0, VOCABM1);
        int e = v & 7;
        int p = atomicAdd(&cur[e], 1);
        int slot = base[e] + p;
        perm[i] = slot;
        rt[slot] = i;
    }
}

// ---------------- gather + fp32->bf16 cast of x into sorted order ----------------
__global__ void gather_cast(const float* __restrict__ x, char* __restrict__ ws) {
    const int* perm = (const int*)(ws + WS_PERM);
    unsigned short* xs = (unsigned short*)(ws + WS_XS);
    int tok = blockIdx.x;
    int slot = perm[tok];
    const float4* src = (const float4*)(x + (size_t)tok * HID);
    uint2* dst = (uint2*)(xs + (size_t)slot * HID);
    for (int j = threadIdx.x; j < HID / 4; j += blockDim.x) {
        float4 f = src[j];
        dst[j] = make_uint2(pk2(f.x, f.y), pk2(f.z, f.w));
    }
}

// ---------------- GEMM1: x_sorted @ gate_up  + fused SwiGLU -> inter (bf16) ----------------
__global__ __launch_bounds__(256, 2)
void gemm1_kernel(char* __restrict__ ws, const float* __restrict__ gup) {
    int nt = *(const int*)(ws + WS_NTILES);
    int by = blockIdx.y;
    if (by >= nt) return;
    int e    = ((const int*)(ws + WS_TEXP))[by];
    int row0 = ((const int*)(ws + WS_TROW))[by];
    int nv   = ((const int*)(ws + WS_TNV))[by];

    const unsigned short* xs = (const unsigned short*)(ws + WS_XS);
    unsigned short* ib = (unsigned short*)(ws + WS_INTER);

    __shared__ __align__(16) unsigned short sA[128 * 32];
    __shared__ __align__(16) unsigned short sBg[128 * 36];
    __shared__ __align__(16) unsigned short sBu[128 * 36];

    int tid = threadIdx.x, w = tid >> 6, l = tid & 63;
    int wm = w & 1, wn = w >> 1, m = l & 15, q = l >> 4;

    const unsigned short* Ab = xs + (size_t)row0 * HID;
    const float* Wg = gup + (size_t)e * HID * (2 * INTER) + (size_t)blockIdx.x * 128;
    const float* Wu = Wg + INTER;

    int c0 = tid, c1 = 256 + tid;
    int ar0 = c0 >> 2, ak0 = (c0 & 3) * 8;
    int ar1 = c1 >> 2, ak1 = (c1 & 3) * 8;
    unsigned short* aD0 = sA + (w * 64) * 8;
    unsigned short* aD1 = sA + (256 + w * 64) * 8;

    int n = tid & 127, kh = (tid >> 7) * 16;

    f32x4 accg[4][4], accu[4][4];
#pragma unroll
    for (int i = 0; i < 4; i++)
#pragma unroll
        for (int j = 0; j < 4; j++) { accg[i][j] = (f32x4)0.0f; accu[i][j] = (f32x4)0.0f; }

    for (int k0 = 0; k0 < HID; k0 += 32) {
        gld16(Ab + (size_t)ar0 * HID + k0 + ak0, aD0);
        gld16(Ab + (size_t)ar1 * HID + k0 + ak1, aD1);
#pragma unroll
        for (int g = 0; g < 4; g++) {
            int kb = kh + g * 4;
            const float* wp = Wg + (size_t)(k0 + kb) * (2 * INTER) + n;
            *(uint2*)(sBg + n * 36 + kb) =
                make_uint2(pk2(wp[0], wp[2 * INTER]), pk2(wp[4 * INTER], wp[6 * INTER]));
            const float* vp = Wu + (size_t)(k0 + kb) * (2 * INTER) + n;
            *(uint2*)(sBu + n * 36 + kb) =
                make_uint2(pk2(vp[0], vp[2 * INTER]), pk2(vp[4 * INTER], vp[6 * INTER]));
        }
        __syncthreads();

        bf16x8 af[4], bg[4], bu[4];
#pragma unroll
        for (int mi = 0; mi < 4; mi++)
            af[mi] = *(const bf16x8*)(sA + ((wm * 64 + mi * 16 + m) * 32 + q * 8));
#pragma unroll
        for (int ni = 0; ni < 4; ni++) {
            int nb = (wn * 64 + ni * 16 + m) * 36 + q * 8;
            bg[ni] = ldfrag(sBg + nb);
            bu[ni] = ldfrag(sBu + nb);
        }
#pragma unroll
        for (int mi = 0; mi < 4; mi++)
#pragma unroll
            for (int ni = 0; ni < 4; ni++) {
                accg[mi][ni] = __builtin_amdgcn_mfma_f32_16x16x32_bf16(af[mi], bg[ni], accg[mi][ni], 0, 0, 0);
                accu[mi][ni] = __builtin_amdgcn_mfma_f32_16x16x32_bf16(af[mi], bu[ni], accu[mi][ni], 0, 0, 0);
            }
        __syncthreads();
    }

#pragma unroll
    for (int mi = 0; mi < 4; mi++)
#pragma unroll
        for (int r = 0; r < 4; r++) {
            int rl = wm * 64 + mi * 16 + q * 4 + r;
            if (rl < nv) {
                size_t o = (size_t)(row0 + rl) * INTER + blockIdx.x * 128 + wn * 64 + m;
#pragma unroll
                for (int ni = 0; ni < 4; ni++) {
                    float g = accg[mi][ni][r];
                    float u = accu[mi][ni][r];
                    float s = g / (1.0f + __expf(-g));
                    ib[o + ni * 16] = f2b(s * u);
                }
            }
        }
}

// ---------------- GEMM2: inter @ down -> scatter to out (fp32) ----------------
__global__ __launch_bounds__(256, 2)
void gemm2_kernel(char* __restrict__ ws, const float* __restrict__ dwn, float* __restrict__ out) {
    int nt = *(const int*)(ws + WS_NTILES);
    int by = blockIdx.y;
    if (by >= nt) return;
    int e    = ((const int*)(ws + WS_TEXP))[by];
    int row0 = ((const int*)(ws + WS_TROW))[by];
    int nv   = ((const int*)(ws + WS_TNV))[by];
    const int* rowtok = (const int*)(ws + WS_ROWTOK);
    const unsigned short* ib = (const unsigned short*)(ws + WS_INTER);

    __shared__ __align__(16) unsigned short sA[128 * 32];
    __shared__ __align__(16) unsigned short sB[128 * 36];

    int tid = threadIdx.x, w = tid >> 6, l = tid & 63;
    int wm = w & 1, wn = w >> 1, m = l & 15, q = l >> 4;

    const unsigned short* Ab = ib + (size_t)row0 * INTER;
    const float* W = dwn + (size_t)e * INTER * HID + (size_t)blockIdx.x * 128;

    int c0 = tid, c1 = 256 + tid;
    int ar0 = c0 >> 2, ak0 = (c0 & 3) * 8;
    int ar1 = c1 >> 2, ak1 = (c1 & 3) * 8;
    unsigned short* aD0 = sA + (w * 64) * 8;
    unsigned short* aD1 = sA + (256 + w * 64) * 8;

    int n = tid & 127, kh = (tid >> 7) * 16;

    f32x4 acc[4][4];
#pragma unroll
    for (int i = 0; i < 4; i++)
#pragma unroll
        for (int j = 0; j < 4; j++) acc[i][j] = (f32x4)0.0f;

    for (int k0 = 0; k0 < INTER; k0 += 32) {
        gld16(Ab + (size_t)ar0 * INTER + k0 + ak0, aD0);
        gld16(Ab + (size_t)ar1 * INTER + k0 + ak1, aD1);
#pragma unroll
        for (int g = 0; g < 4; g++) {
            int kb = kh + g * 4;
            const float* wp = W + (size_t)(k0 + kb) * HID + n;
            *(uint2*)(sB + n * 36 + kb) =
                make_uint2(pk2(wp[0], wp[HID]), pk2(wp[2 * HID], wp[3 * HID]));
        }
        __syncthreads();

        bf16x8 af[4], bfr[4];
#pragma unroll
        for (int mi = 0; mi < 4; mi++)
            af[mi] = *(const bf16x8*)(sA + ((wm * 64 + mi * 16 + m) * 32 + q * 8));
#pragma unroll
        for (int ni = 0; ni < 4; ni++)
            bfr[ni] = ldfrag(sB + (wn * 64 + ni * 16 + m) * 36 + q * 8);
#pragma unroll
        for (int mi = 0; mi < 4; mi++)
#pragma unroll
            for (int ni = 0; ni < 4; ni++)
                acc[mi][ni] = __builtin_amdgcn_mfma_f32_16x16x32_bf16(af[mi], bfr[ni], acc[mi][ni], 0, 0, 0);
        __syncthreads();
    }

#pragma unroll
    for (int mi = 0; mi < 4; mi++)
#pragma unroll
        for (int r = 0; r < 4; r++) {
            int rl = wm * 64 + mi * 16 + q * 4 + r;
            if (rl < nv) {
                int tok = rowtok[row0 + rl];
                size_t o = (size_t)tok * HID + blockIdx.x * 128 + wn * 64 + m;
#pragma unroll
                for (int ni = 0; ni < 4; ni++) out[o + ni * 16] = acc[mi][ni][r];
            }
        }
}

extern "C" void kernel_launch(void* const* d_in, const int* in_sizes, int n_in,
                              void* d_out, int out_size, void* d_ws, size_t ws_size,
                              hipStream_t stream) {
    const float* x   = (const float*)d_in[0];
    const int*   ids = (const int*)d_in[1];
    const float* gup = (const float*)d_in[2];
    const float* dwn = (const float*)d_in[3];
    char* ws = (char*)d_ws;
    if (ws_size < WS_NEED) return;  // workspace too small: fail loudly

    hipLaunchKernelGGL(route_kernel, dim3(1), dim3(1024), 0, stream, ids, ws);
    hipLaunchKernelGGL(gather_cast, dim3(TOKENS), dim3(256), 0, stream, x, ws);
    hipLaunchKernelGGL(gemm1_kernel, dim3(16, MAXTILES), dim3(256), 0, stream, ws, gup);
    hipLaunchKernelGGL(gemm2_kernel, dim3(32, MAXTILES), dim3(256), 0, stream, ws, dwn, (float*)d_out);
}